// Round 1
// 865.448 us; speedup vs baseline: 1.0754x; 1.0754x over previous
//
#include <hip/hip_runtime.h>

#define D 64
#define LN_EPS 1e-5f
#define DIV_EPS 1e-6f

typedef __attribute__((ext_vector_type(8))) short bf16x8;
typedef __attribute__((ext_vector_type(4))) float f32x4;

// f32 -> bf16 round-to-nearest-even
__device__ __forceinline__ short f2bf(float f) {
  unsigned u = __float_as_uint(f);
  unsigned r = (u + 0x7fffu + ((u >> 16) & 1u)) >> 16;
  return (short)r;
}

__device__ __forceinline__ f32x4 ntld4(const float* p) {
  return __builtin_nontemporal_load((const f32x4*)p);
}

// sum across a 16-lane group (masks < 16 stay inside the group)
__device__ __forceinline__ float gsum16(float v) {
#pragma unroll
  for (int m = 1; m < 16; m <<= 1) v += __shfl_xor(v, m, 64);
  return v;
}

// B-fragment for mfma_f32_16x16x32_bf16 from row-major W[64][64] ([k][c]).
// Lane holds B[k = s*32 + (lane>>4)*8 + j][c = n0*16 + (lane&15)], j=0..7.
__device__ __forceinline__ bf16x8 load_bfrag(const float* __restrict__ W,
                                             int s, int n0, int lane) {
  const int c = n0 * 16 + (lane & 15);
  const int k0 = s * 32 + ((lane >> 4) << 3);
  bf16x8 b;
#pragma unroll
  for (int j = 0; j < 8; ++j) b[j] = f2bf(W[(k0 + j) * D + c]);
  return b;
}

// A-fragments (2 k-steps) for 16 consecutive rows of X starting at r0.
__device__ __forceinline__ void load_afrags(const float* __restrict__ X,
                                            size_t r0, int lane, bf16x8& a0,
                                            bf16x8& a1) {
  const int q = lane >> 4, m = lane & 15;
  const float* rb = X + (r0 + m) * D;
  const float4* p0 = (const float4*)(rb + q * 8);
  const float4* p1 = (const float4*)(rb + 32 + q * 8);
  float4 v0 = p0[0], v1 = p0[1], v2 = p1[0], v3 = p1[1];
  a0 = (bf16x8){f2bf(v0.x), f2bf(v0.y), f2bf(v0.z), f2bf(v0.w),
                f2bf(v1.x), f2bf(v1.y), f2bf(v1.z), f2bf(v1.w)};
  a1 = (bf16x8){f2bf(v2.x), f2bf(v2.y), f2bf(v2.z), f2bf(v2.w),
                f2bf(v3.x), f2bf(v3.y), f2bf(v3.z), f2bf(v3.w)};
}

// Fused node projections: o{0..3} = h @ W{0..3} + b{0..3}. One wave = 16 rows.
__global__ __launch_bounds__(256, 1) void node_proj_mfma(
    const float* __restrict__ h, const float* __restrict__ W0,
    const float* __restrict__ Bb0, const float* __restrict__ W1,
    const float* __restrict__ Bb1, const float* __restrict__ W2,
    const float* __restrict__ Bb2, const float* __restrict__ W3,
    const float* __restrict__ Bb3, float* __restrict__ o0,
    float* __restrict__ o1, float* __restrict__ o2, float* __restrict__ o3,
    int N) {
  const int lane = threadIdx.x & 63;
  const int q = lane >> 4, m = lane & 15;
  const int wave = blockIdx.x * 4 + (threadIdx.x >> 6);
  const int nw = gridDim.x * 4;
  const float* Ws[4] = {W0, W1, W2, W3};
  const float* Bs[4] = {Bb0, Bb1, Bb2, Bb3};
  float* Os[4] = {o0, o1, o2, o3};
  bf16x8 bf[4][2][4];
  float bias[4][4];
#pragma unroll
  for (int mat = 0; mat < 4; ++mat) {
#pragma unroll
    for (int s = 0; s < 2; ++s)
#pragma unroll
      for (int n0 = 0; n0 < 4; ++n0)
        bf[mat][s][n0] = load_bfrag(Ws[mat], s, n0, lane);
#pragma unroll
    for (int n0 = 0; n0 < 4; ++n0) bias[mat][n0] = Bs[mat][n0 * 16 + m];
  }
  for (int r0 = wave * 16; r0 < N; r0 += nw * 16) {
    bf16x8 a0, a1;
    load_afrags(h, (size_t)r0, lane, a0, a1);
#pragma unroll
    for (int mat = 0; mat < 4; ++mat) {
      f32x4 acc[4];
#pragma unroll
      for (int n0 = 0; n0 < 4; ++n0) {
        acc[n0] = (f32x4){0.f, 0.f, 0.f, 0.f};
        acc[n0] = __builtin_amdgcn_mfma_f32_16x16x32_bf16(a0, bf[mat][0][n0],
                                                          acc[n0], 0, 0, 0);
        acc[n0] = __builtin_amdgcn_mfma_f32_16x16x32_bf16(a1, bf[mat][1][n0],
                                                          acc[n0], 0, 0, 0);
      }
      float* Om = Os[mat];
#pragma unroll
      for (int n0 = 0; n0 < 4; ++n0)
#pragma unroll
        for (int r = 0; r < 4; ++r)
          Om[(size_t)(r0 + q * 4 + r) * D + n0 * 16 + m] =
              acc[n0][r] + bias[mat][n0];
    }
  }
}

// Edge pipeline v3.
// Phase 1: MFMA GEMV (e@B3w) for this wave's 16 edges; raw f32 e-tile stashed
//          in LDS (es) for the residual — no global re-read of e.
// Phase 2: 4 edges in flight — 16-lane group q owns MFMA C rows 4q..4q+3
//          directly from acc registers (C layout: acc[n0][r] = row 4q+r,
//          col n0*16+m, harness-verified). Lane handles channels m+16k.
//          LN reduce = 3 local adds + 4 intra-group shuffles.
__global__ __launch_bounds__(256, 3) void edge_mfma3(
    const float* __restrict__ e, const int* __restrict__ src,
    const int* __restrict__ dst, const float* __restrict__ B1h,
    const float* __restrict__ B2h, const float* __restrict__ A2h,
    const float* __restrict__ W3, const float* __restrict__ B3b,
    const float* __restrict__ g, const float* __restrict__ bta,
    float* __restrict__ eout, float* __restrict__ ssh, float* __restrict__ ss,
    int E) {
  // stride 68 floats: phase-2 scalar reads land 2-way on banks (free);
  // phase-1 f32x4 writes are 16B-aligned (68*4 % 16 == 0).
  __shared__ float es[4][16][68];
  const int lane = threadIdx.x & 63;
  const int q = lane >> 4, m = lane & 15;
  const int wid = threadIdx.x >> 6;
  const int gw = blockIdx.x * 4 + wid;
  const int nw = gridDim.x * 4;
  bf16x8 bf[2][4];
#pragma unroll
  for (int s = 0; s < 2; ++s)
#pragma unroll
    for (int n0 = 0; n0 < 4; ++n0) bf[s][n0] = load_bfrag(W3, s, n0, lane);
  float bb[4], gl[4], bl[4];
#pragma unroll
  for (int k = 0; k < 4; ++k) {
    const int c = m + 16 * k;
    bb[k] = B3b[c];
    gl[k] = g[c];
    bl[k] = bta[c];
  }
  for (int e0 = gw * 16; e0 < E; e0 += nw * 16) {
    // ---- phase 1: nt-load e tile, stash f32 copy to LDS, MFMA ----
    const float* rb = e + (size_t)(e0 + m) * D;
    f32x4 v0 = ntld4(rb + q * 8);
    f32x4 v1 = ntld4(rb + q * 8 + 4);
    f32x4 v2 = ntld4(rb + 32 + q * 8);
    f32x4 v3 = ntld4(rb + 32 + q * 8 + 4);
    f32x4* erow = (f32x4*)&es[wid][m][0];
    erow[q * 2] = v0;
    erow[q * 2 + 1] = v1;
    erow[8 + q * 2] = v2;
    erow[8 + q * 2 + 1] = v3;
    bf16x8 a0 = (bf16x8){f2bf(v0[0]), f2bf(v0[1]), f2bf(v0[2]), f2bf(v0[3]),
                         f2bf(v1[0]), f2bf(v1[1]), f2bf(v1[2]), f2bf(v1[3])};
    bf16x8 a1 = (bf16x8){f2bf(v2[0]), f2bf(v2[1]), f2bf(v2[2]), f2bf(v2[3]),
                         f2bf(v3[0]), f2bf(v3[1]), f2bf(v3[2]), f2bf(v3[3])};
    f32x4 acc[4];
#pragma unroll
    for (int n0 = 0; n0 < 4; ++n0) {
      acc[n0] = (f32x4){0.f, 0.f, 0.f, 0.f};
      acc[n0] =
          __builtin_amdgcn_mfma_f32_16x16x32_bf16(a0, bf[0][n0], acc[n0], 0, 0, 0);
      acc[n0] =
          __builtin_amdgcn_mfma_f32_16x16x32_bf16(a1, bf[1][n0], acc[n0], 0, 0, 0);
    }
    // tile indices: lane t<16 holds src/dst of edge e0+t; broadcast via shfl
    const int sv = src[e0 + m];
    const int dv = dst[e0 + m];
    // ---- phase 2: 4 edges concurrently (one per 16-lane group) ----
#pragma unroll
    for (int r = 0; r < 4; ++r) {
      const int tr = q * 4 + r;  // this group's tile row
      const int sN = __shfl(sv, tr, 64);
      const int dN = __shfl(dv, tr, 64);
      const size_t sb = (size_t)sN * D, db = (size_t)dN * D;
      float x[4], a2[4], part = 0.f;
#pragma unroll
      for (int k = 0; k < 4; ++k) {
        const int c = m + 16 * k;
        x[k] = acc[k][r] + bb[k] + B1h[sb + c] + B2h[db + c];
        a2[k] = A2h[sb + c];
        part += x[k];
      }
      const float mu = gsum16(part) * (1.f / 64.f);
      float dx[4], vp = 0.f;
#pragma unroll
      for (int k = 0; k < 4; ++k) {
        dx[k] = x[k] - mu;
        vp += dx[k] * dx[k];
      }
      const float rs = rsqrtf(gsum16(vp) * (1.f / 64.f) + LN_EPS);
      const size_t eb = (size_t)(e0 + tr) * D;
#pragma unroll
      for (int k = 0; k < 4; ++k) {
        const int c = m + 16 * k;
        float y = fmaxf(dx[k] * rs * gl[k] + bl[k], 0.f) + es[wid][tr][c];
        __builtin_nontemporal_store(y, eout + eb + c);
        const float sg = 1.f / (1.f + __expf(-y));
        atomicAdd(&ssh[db + c], a2[k] * sg);
        atomicAdd(&ss[db + c], sg);
      }
    }
  }
}

// h_out = relu(LN(A1h + ssh/(ss+eps))) + h — 4 rows per wave in flight,
// 16-lane groups, float4 streams.
__global__ __launch_bounds__(256) void node_out2(
    const float* __restrict__ h, const float* __restrict__ A1h,
    const float* __restrict__ ssh, const float* __restrict__ ss,
    const float* __restrict__ g, const float* __restrict__ bta,
    float* __restrict__ hout, int n) {
  const int lane = threadIdx.x & 63;
  const int q = lane >> 4, m = lane & 15;
  const int wave = blockIdx.x * 4 + (threadIdx.x >> 6);
  const int nw = gridDim.x * 4;
  const f32x4 gl = ((const f32x4*)g)[m];
  const f32x4 bl = ((const f32x4*)bta)[m];
  for (int n0 = wave * 4; n0 < n; n0 += nw * 4) {
    const int row = n0 + q;  // group-uniform guard
    if (row >= n) continue;
    const size_t base = (size_t)row * D + m * 4;
    f32x4 a1 = ntld4(A1h + base);
    f32x4 s1 = ntld4(ssh + base);
    f32x4 s2 = ntld4(ss + base);
    f32x4 hv = ntld4(h + base);
    float x[4], part = 0.f;
#pragma unroll
    for (int k = 0; k < 4; ++k) {
      x[k] = a1[k] + s1[k] / (s2[k] + DIV_EPS);
      part += x[k];
    }
    const float mu = gsum16(part) * (1.f / 64.f);
    float dx[4], vp = 0.f;
#pragma unroll
    for (int k = 0; k < 4; ++k) {
      dx[k] = x[k] - mu;
      vp += dx[k] * dx[k];
    }
    const float rs = rsqrtf(gsum16(vp) * (1.f / 64.f) + LN_EPS);
    f32x4 y;
#pragma unroll
    for (int k = 0; k < 4; ++k)
      y[k] = fmaxf(dx[k] * rs * gl[k] + bl[k], 0.f) + hv[k];
    __builtin_nontemporal_store(y, (f32x4*)(hout + base));
  }
}

extern "C" void kernel_launch(void* const* d_in, const int* in_sizes, int n_in,
                              void* d_out, int out_size, void* d_ws,
                              size_t ws_size, hipStream_t stream) {
  const float* h = (const float*)d_in[0];
  const float* e = (const float*)d_in[1];
  const int* src = (const int*)d_in[2];
  const int* dst = (const int*)d_in[3];
  const float* A1w = (const float*)d_in[4];
  const float* A1b = (const float*)d_in[5];
  const float* A2w = (const float*)d_in[6];
  const float* A2b = (const float*)d_in[7];
  const float* B1w = (const float*)d_in[8];
  const float* B1b = (const float*)d_in[9];
  const float* B2w = (const float*)d_in[10];
  const float* B2b = (const float*)d_in[11];
  const float* B3w = (const float*)d_in[12];
  const float* B3b = (const float*)d_in[13];
  const float* ln_e_g = (const float*)d_in[14];
  const float* ln_e_b = (const float*)d_in[15];
  const float* ln_h_g = (const float*)d_in[16];
  const float* ln_h_b = (const float*)d_in[17];

  const int N = in_sizes[0] / D;  // 100000
  const int E = in_sizes[1] / D;  // 1000000

  float* ws = (float*)d_ws;
  float* A1h = ws;
  float* A2h = ws + (size_t)N * D;
  float* B1h = ws + 2 * (size_t)N * D;
  float* B2h = ws + 3 * (size_t)N * D;
  float* ssh = ws + 4 * (size_t)N * D;
  float* ss = ws + 5 * (size_t)N * D;

  float* hout = (float*)d_out;
  float* eout = (float*)d_out + (size_t)N * D;

  hipMemsetAsync(ssh, 0, 2 * (size_t)N * D * sizeof(float), stream);

  node_proj_mfma<<<1563, 256, 0, stream>>>(h, B1w, B1b, B2w, B2b, A1w, A1b,
                                           A2w, A2b, B1h, B2h, A1h, A2h, N);
  // 3907 blocks: 15628 waves x 16 edges -> ~4 tiles/wave, balanced
  edge_mfma3<<<3907, 256, 0, stream>>>(e, src, dst, B1h, B2h, A2h, B3w, B3b,
                                       ln_e_g, ln_e_b, eout, ssh, ss, E);
  node_out2<<<2048, 256, 0, stream>>>(h, A1h, ssh, ss, ln_h_g, ln_h_b, hout, N);
}

// Round 2
// 793.545 us; speedup vs baseline: 1.1729x; 1.0906x over previous
//
#include <hip/hip_runtime.h>

#define D 64
#define LN_EPS 1e-5f
#define DIV_EPS 1e-6f

typedef __attribute__((ext_vector_type(8))) short bf16x8;
typedef __attribute__((ext_vector_type(4))) float f32x4;

// f32 -> bf16 round-to-nearest-even
__device__ __forceinline__ short f2bf(float f) {
  unsigned u = __float_as_uint(f);
  unsigned r = (u + 0x7fffu + ((u >> 16) & 1u)) >> 16;
  return (short)r;
}

__device__ __forceinline__ f32x4 ntld4(const float* p) {
  return __builtin_nontemporal_load((const f32x4*)p);
}

// sum across a 16-lane group (xor masks < 16 stay inside the group)
__device__ __forceinline__ float gsum16(float v) {
#pragma unroll
  for (int m = 1; m < 16; m <<= 1) v += __shfl_xor(v, m, 64);
  return v;
}

// B-fragment for mfma_f32_16x16x32_bf16 from row-major W[64][64] ([k][c]).
// Lane holds B[k = s*32 + (lane>>4)*8 + j][c = n0*16 + (lane&15)], j=0..7.
__device__ __forceinline__ bf16x8 load_bfrag(const float* __restrict__ W,
                                             int s, int n0, int lane) {
  const int c = n0 * 16 + (lane & 15);
  const int k0 = s * 32 + ((lane >> 4) << 3);
  bf16x8 b;
#pragma unroll
  for (int j = 0; j < 8; ++j) b[j] = f2bf(W[(k0 + j) * D + c]);
  return b;
}

// A-fragments (2 k-steps) for 16 consecutive rows of X starting at r0.
__device__ __forceinline__ void load_afrags(const float* __restrict__ X,
                                            size_t r0, int lane, bf16x8& a0,
                                            bf16x8& a1) {
  const int q = lane >> 4, m = lane & 15;
  const float* rb = X + (r0 + m) * D;
  const float4* p0 = (const float4*)(rb + q * 8);
  const float4* p1 = (const float4*)(rb + 32 + q * 8);
  float4 v0 = p0[0], v1 = p0[1], v2 = p1[0], v3 = p1[1];
  a0 = (bf16x8){f2bf(v0.x), f2bf(v0.y), f2bf(v0.z), f2bf(v0.w),
                f2bf(v1.x), f2bf(v1.y), f2bf(v1.z), f2bf(v1.w)};
  a1 = (bf16x8){f2bf(v2.x), f2bf(v2.y), f2bf(v2.z), f2bf(v2.w),
                f2bf(v3.x), f2bf(v3.y), f2bf(v3.z), f2bf(v3.w)};
}

// Node projections, one matrix PER WAVE (wid = mat): 32 VGPRs of weight
// fragments instead of 128 -> ~5 waves/SIMD latency hiding. All 4 waves of a
// block read the same 16 h-rows (L1 hit for waves 1-3).
__global__ __launch_bounds__(256) void node_proj2(
    const float* __restrict__ h, const float* __restrict__ W0,
    const float* __restrict__ Bb0, const float* __restrict__ W1,
    const float* __restrict__ Bb1, const float* __restrict__ W2,
    const float* __restrict__ Bb2, const float* __restrict__ W3,
    const float* __restrict__ Bb3, float* __restrict__ o0,
    float* __restrict__ o1, float* __restrict__ o2, float* __restrict__ o3,
    int N) {
  const int lane = threadIdx.x & 63;
  const int q = lane >> 4, m = lane & 15;
  const int wid = threadIdx.x >> 6;  // matrix index
  const float* Ws[4] = {W0, W1, W2, W3};
  const float* Bs[4] = {Bb0, Bb1, Bb2, Bb3};
  float* Os[4] = {o0, o1, o2, o3};
  const float* W = Ws[wid];
  float* Om = Os[wid];
  bf16x8 bf[2][4];
#pragma unroll
  for (int s = 0; s < 2; ++s)
#pragma unroll
    for (int n0 = 0; n0 < 4; ++n0) bf[s][n0] = load_bfrag(W, s, n0, lane);
  float bias[4];
#pragma unroll
  for (int n0 = 0; n0 < 4; ++n0) bias[n0] = Bs[wid][n0 * 16 + m];
  for (int r0 = blockIdx.x * 16; r0 < N; r0 += gridDim.x * 16) {
    bf16x8 a0, a1;
    load_afrags(h, (size_t)r0, lane, a0, a1);
    f32x4 acc[4];
#pragma unroll
    for (int n0 = 0; n0 < 4; ++n0) {
      acc[n0] = (f32x4){0.f, 0.f, 0.f, 0.f};
      acc[n0] =
          __builtin_amdgcn_mfma_f32_16x16x32_bf16(a0, bf[0][n0], acc[n0], 0, 0, 0);
      acc[n0] =
          __builtin_amdgcn_mfma_f32_16x16x32_bf16(a1, bf[1][n0], acc[n0], 0, 0, 0);
    }
#pragma unroll
    for (int n0 = 0; n0 < 4; ++n0)
#pragma unroll
      for (int r = 0; r < 4; ++r)
        Om[(size_t)(r0 + q * 4 + r) * D + n0 * 16 + m] = acc[n0][r] + bias[n0];
  }
}

// ---- CSR build: histogram -> scan -> placement ----

__global__ __launch_bounds__(256) void hist_kernel(const int* __restrict__ dst,
                                                   int* __restrict__ cnt,
                                                   int E) {
  for (int i = blockIdx.x * blockDim.x + threadIdx.x; i < E;
       i += gridDim.x * blockDim.x)
    atomicAdd(&cnt[dst[i]], 1);
}

#define SCAN_B 256
// per-block exclusive scan of counts; block totals to bsum
__global__ __launch_bounds__(SCAN_B) void scan1(const int* __restrict__ cnt,
                                                int* __restrict__ rs,
                                                int* __restrict__ bsum, int n) {
  __shared__ int s[SCAN_B];
  const int i = blockIdx.x * SCAN_B + threadIdx.x;
  const int v = (i < n) ? cnt[i] : 0;
  s[threadIdx.x] = v;
  __syncthreads();
#pragma unroll
  for (int off = 1; off < SCAN_B; off <<= 1) {
    int t = (threadIdx.x >= off) ? s[threadIdx.x - off] : 0;
    __syncthreads();
    s[threadIdx.x] += t;
    __syncthreads();
  }
  if (i < n) rs[i] = s[threadIdx.x] - v;
  if (threadIdx.x == SCAN_B - 1) bsum[blockIdx.x] = s[SCAN_B - 1];
}

// exclusive scan of block sums (nb <= 512), one block
__global__ __launch_bounds__(512) void scan2(int* __restrict__ bsum, int nb) {
  __shared__ int s[512];
  const int v = (threadIdx.x < nb) ? bsum[threadIdx.x] : 0;
  s[threadIdx.x] = v;
  __syncthreads();
#pragma unroll
  for (int off = 1; off < 512; off <<= 1) {
    int t = (threadIdx.x >= off) ? s[threadIdx.x - off] : 0;
    __syncthreads();
    s[threadIdx.x] += t;
    __syncthreads();
  }
  if (threadIdx.x < nb) bsum[threadIdx.x] = s[threadIdx.x] - v;
}

// add block offsets; init cursor; rs[n] = E
__global__ __launch_bounds__(SCAN_B) void scan3(int* __restrict__ rs,
                                                int* __restrict__ cur,
                                                const int* __restrict__ bsum,
                                                int n, int E) {
  const int i = blockIdx.x * SCAN_B + threadIdx.x;
  if (i < n) {
    const int v = rs[i] + bsum[blockIdx.x];
    rs[i] = v;
    cur[i] = v;
  }
  if (blockIdx.x == 0 && threadIdx.x == 0) rs[n] = E;
}

__global__ __launch_bounds__(256) void place_kernel(const int* __restrict__ dst,
                                                    int* __restrict__ cur,
                                                    int* __restrict__ list,
                                                    int E) {
  for (int i = blockIdx.x * blockDim.x + threadIdx.x; i < E;
       i += gridDim.x * blockDim.x) {
    const int p = atomicAdd(&cur[dst[i]], 1);
    list[p] = i;
  }
}

// Edge pipeline v4: MFMA + LN + residual + eout store. NO aggregation here
// (no atomics, no A2h gather) — aggregation is a separate gather pass.
__global__ __launch_bounds__(256, 4) void edge_mfma4(
    const float* __restrict__ e, const int* __restrict__ src,
    const int* __restrict__ dst, const float* __restrict__ B1h,
    const float* __restrict__ B2h, const float* __restrict__ W3,
    const float* __restrict__ B3b, const float* __restrict__ g,
    const float* __restrict__ bta, float* __restrict__ eout, int E) {
  __shared__ float es[4][16][68];
  const int lane = threadIdx.x & 63;
  const int q = lane >> 4, m = lane & 15;
  const int wid = threadIdx.x >> 6;
  const int gw = blockIdx.x * 4 + wid;
  const int nw = gridDim.x * 4;
  bf16x8 bf[2][4];
#pragma unroll
  for (int s = 0; s < 2; ++s)
#pragma unroll
    for (int n0 = 0; n0 < 4; ++n0) bf[s][n0] = load_bfrag(W3, s, n0, lane);
  float bb[4], gl[4], bl[4];
#pragma unroll
  for (int k = 0; k < 4; ++k) {
    const int c = m + 16 * k;
    bb[k] = B3b[c];
    gl[k] = g[c];
    bl[k] = bta[c];
  }
  for (int e0 = gw * 16; e0 < E; e0 += nw * 16) {
    // ---- phase 1: nt-load e tile, stash f32 copy in LDS, MFMA ----
    const float* rb = e + (size_t)(e0 + m) * D;
    f32x4 v0 = ntld4(rb + q * 8);
    f32x4 v1 = ntld4(rb + q * 8 + 4);
    f32x4 v2 = ntld4(rb + 32 + q * 8);
    f32x4 v3 = ntld4(rb + 32 + q * 8 + 4);
    f32x4* erow = (f32x4*)&es[wid][m][0];
    erow[q * 2] = v0;
    erow[q * 2 + 1] = v1;
    erow[8 + q * 2] = v2;
    erow[8 + q * 2 + 1] = v3;
    bf16x8 a0 = (bf16x8){f2bf(v0[0]), f2bf(v0[1]), f2bf(v0[2]), f2bf(v0[3]),
                         f2bf(v1[0]), f2bf(v1[1]), f2bf(v1[2]), f2bf(v1[3])};
    bf16x8 a1 = (bf16x8){f2bf(v2[0]), f2bf(v2[1]), f2bf(v2[2]), f2bf(v2[3]),
                         f2bf(v3[0]), f2bf(v3[1]), f2bf(v3[2]), f2bf(v3[3])};
    f32x4 acc[4];
#pragma unroll
    for (int n0 = 0; n0 < 4; ++n0) {
      acc[n0] = (f32x4){0.f, 0.f, 0.f, 0.f};
      acc[n0] =
          __builtin_amdgcn_mfma_f32_16x16x32_bf16(a0, bf[0][n0], acc[n0], 0, 0, 0);
      acc[n0] =
          __builtin_amdgcn_mfma_f32_16x16x32_bf16(a1, bf[1][n0], acc[n0], 0, 0, 0);
    }
    const int sv = src[e0 + m];
    const int dv = dst[e0 + m];
    // ---- phase 2: 4 edges concurrently, acc consumed from registers ----
#pragma unroll
    for (int r = 0; r < 4; ++r) {
      const int tr = q * 4 + r;
      const int sN = __shfl(sv, tr, 64);
      const int dN = __shfl(dv, tr, 64);
      const size_t sb = (size_t)sN * D, db = (size_t)dN * D;
      float x[4], part = 0.f;
#pragma unroll
      for (int k = 0; k < 4; ++k) {
        const int c = m + 16 * k;
        x[k] = acc[k][r] + bb[k] + B1h[sb + c] + B2h[db + c];
        part += x[k];
      }
      const float mu = gsum16(part) * (1.f / 64.f);
      float dx[4], vp = 0.f;
#pragma unroll
      for (int k = 0; k < 4; ++k) {
        dx[k] = x[k] - mu;
        vp += dx[k] * dx[k];
      }
      const float rs = rsqrtf(gsum16(vp) * (1.f / 64.f) + LN_EPS);
      const size_t eb = (size_t)(e0 + tr) * D;
#pragma unroll
      for (int k = 0; k < 4; ++k) {
        const int c = m + 16 * k;
        // plain store (not nt): aggregate pass re-reads eout; let L2/L3 keep it
        eout[eb + c] = fmaxf(dx[k] * rs * gl[k] + bl[k], 0.f) + es[wid][tr][c];
      }
    }
  }
}

// Aggregation + node output, fused. One 16-lane group per node: walk the
// node's incoming-edge list, recompute sigma = sigmoid(eout), accumulate
// sum(A2h[src]*sg) and sum(sg) in registers, then LN + relu + residual.
__global__ __launch_bounds__(256) void aggregate_out(
    const float* __restrict__ h, const float* __restrict__ A1h,
    const float* __restrict__ A2h, const float* __restrict__ eout,
    const int* __restrict__ rs, const int* __restrict__ list,
    const int* __restrict__ src, const float* __restrict__ g,
    const float* __restrict__ bta, float* __restrict__ hout, int N) {
  const int lane = threadIdx.x & 63;
  const int q = lane >> 4, m = lane & 15;
  const int wave = blockIdx.x * 4 + (threadIdx.x >> 6);
  const int nw = gridDim.x * 4;
  const f32x4 gl = ((const f32x4*)g)[m];
  const f32x4 bl = ((const f32x4*)bta)[m];
  for (int n = wave * 4 + q; n < N; n += nw * 4) {
    const int s = rs[n], t = rs[n + 1];
    f32x4 acc0 = (f32x4){0.f, 0.f, 0.f, 0.f};
    f32x4 acc1 = (f32x4){0.f, 0.f, 0.f, 0.f};
    for (int b = s; b < t; b += 16) {
      const int nn = min(16, t - b);
      // batch-load up to 16 edge ids + their src nodes (lanes m < nn)
      const int jm = (m < nn) ? list[b + m] : 0;
      const int sm = (m < nn) ? src[jm] : 0;
      for (int u = 0; u < nn; ++u) {
        const int jj = __shfl(jm, q * 16 + u, 64);
        const int sj = __shfl(sm, q * 16 + u, 64);
        const f32x4 y = *(const f32x4*)(eout + (size_t)jj * D + m * 4);
        const f32x4 a2 = *(const f32x4*)(A2h + (size_t)sj * D + m * 4);
#pragma unroll
        for (int k = 0; k < 4; ++k) {
          const float sg = 1.f / (1.f + __expf(-y[k]));
          acc0[k] += sg;
          acc1[k] += a2[k] * sg;
        }
      }
    }
    const size_t base = (size_t)n * D + m * 4;
    const f32x4 a1 = ntld4(A1h + base);
    const f32x4 hv = ntld4(h + base);
    float x[4], part = 0.f;
#pragma unroll
    for (int k = 0; k < 4; ++k) {
      x[k] = a1[k] + acc1[k] / (acc0[k] + DIV_EPS);
      part += x[k];
    }
    const float mu = gsum16(part) * (1.f / 64.f);
    float dx[4], vp = 0.f;
#pragma unroll
    for (int k = 0; k < 4; ++k) {
      dx[k] = x[k] - mu;
      vp += dx[k] * dx[k];
    }
    const float rsv = rsqrtf(gsum16(vp) * (1.f / 64.f) + LN_EPS);
    f32x4 y;
#pragma unroll
    for (int k = 0; k < 4; ++k)
      y[k] = fmaxf(dx[k] * rsv * gl[k] + bl[k], 0.f) + hv[k];
    __builtin_nontemporal_store(y, (f32x4*)(hout + base));
  }
}

extern "C" void kernel_launch(void* const* d_in, const int* in_sizes, int n_in,
                              void* d_out, int out_size, void* d_ws,
                              size_t ws_size, hipStream_t stream) {
  const float* h = (const float*)d_in[0];
  const float* e = (const float*)d_in[1];
  const int* src = (const int*)d_in[2];
  const int* dst = (const int*)d_in[3];
  const float* A1w = (const float*)d_in[4];
  const float* A1b = (const float*)d_in[5];
  const float* A2w = (const float*)d_in[6];
  const float* A2b = (const float*)d_in[7];
  const float* B1w = (const float*)d_in[8];
  const float* B1b = (const float*)d_in[9];
  const float* B2w = (const float*)d_in[10];
  const float* B2b = (const float*)d_in[11];
  const float* B3w = (const float*)d_in[12];
  const float* B3b = (const float*)d_in[13];
  const float* ln_e_g = (const float*)d_in[14];
  const float* ln_e_b = (const float*)d_in[15];
  const float* ln_h_g = (const float*)d_in[16];
  const float* ln_h_b = (const float*)d_in[17];

  const int N = in_sizes[0] / D;  // 100000
  const int E = in_sizes[1] / D;  // 1000000

  float* ws = (float*)d_ws;
  float* A1h = ws;
  float* A2h = ws + (size_t)N * D;
  float* B1h = ws + 2 * (size_t)N * D;
  float* B2h = ws + 3 * (size_t)N * D;
  int* ip = (int*)(ws + 4 * (size_t)N * D);
  int* rs = ip;               // [N+1]  row starts
  int* cur = ip + (N + 1);    // [N]    counts, then cursors
  int* list = cur + N;        // [E]    edge ids bucketed by dst
  int* bsum = list + E;       // [512]  scan block sums

  float* hout = (float*)d_out;
  float* eout = (float*)d_out + (size_t)N * D;

  const int nb = (N + SCAN_B - 1) / SCAN_B;  // 391

  hipMemsetAsync(cur, 0, (size_t)N * sizeof(int), stream);

  node_proj2<<<3125, 256, 0, stream>>>(h, B1w, B1b, B2w, B2b, A1w, A1b, A2w,
                                       A2b, B1h, B2h, A1h, A2h, N);
  hist_kernel<<<512, 256, 0, stream>>>(dst, cur, E);
  scan1<<<nb, SCAN_B, 0, stream>>>(cur, rs, bsum, N);
  scan2<<<1, 512, 0, stream>>>(bsum, nb);
  scan3<<<nb, SCAN_B, 0, stream>>>(rs, cur, bsum, N, E);
  place_kernel<<<512, 256, 0, stream>>>(dst, cur, list, E);
  edge_mfma4<<<3907, 256, 0, stream>>>(e, src, dst, B1h, B2h, B3w, B3b, ln_e_g,
                                       ln_e_b, eout, E);
  aggregate_out<<<4096, 256, 0, stream>>>(h, A1h, A2h, eout, rs, list, src,
                                          ln_h_g, ln_h_b, hout, N);
}